// Round 7
// baseline (495.949 us; speedup 1.0000x reference)
//
#include <hip/hip_runtime.h>
#include <math.h>

#define EPS 1e-6f

constexpr int B    = 8;
constexpr int F    = 64;
constexpr int C    = 16;
constexpr int L    = 65536;      // 256*256
constexpr int TPB  = 256;
constexpr int NREP = 8;          // atomic-target replicas
constexpr int BLKF = 256;        // l-floats per block (64 lanes x float4 per f-row)
constexpr int FB   = 8;          // f-rows per LDS tile (8 KB)
constexpr int NT   = F / FB;     // 8 tiles

// Direct global->LDS DMA, 16 B per lane. LDS dst is the WAVE-UNIFORM row base
// (HW adds lane*16); global src is per-lane.
__device__ __forceinline__ void dma16(float* ldsdst, const float* gsrc) {
    __builtin_amdgcn_global_load_lds(
        (const __attribute__((address_space(1))) void*)gsrc,
        (__attribute__((address_space(3))) void*)ldsdst,
        16, 0, 0);
}

// Stage 1: partials num[b,c] = sum_l (e2 - 2*dot)*r, den[b,c] = sum_l r.
// ws layout: float ws[NREP][2][2][B][C] -> [rep][term][num/den][b][c]
//
// R1-R6 lesson: register-staged loads never get deep MLP without blowing the
// VGPR budget. So: global_load_lds double-buffer (loads never touch VGPRs),
// raw s_barrier + counted vmcnt(2) (never 0 in the loop) so tile t+1 streams
// while tile t is computed. 8 blocks/CU x 16 KB in flight = ~128 KB/CU >> the
// ~9 KB BW*latency product -> BW-bound by construction.
__global__ __launch_bounds__(TPB, 8)
void cross_partial_kernel(const float* __restrict__ embed1,
                          const float* __restrict__ rids1,
                          const float* __restrict__ embed2,
                          const float* __restrict__ rids2,
                          const float* __restrict__ codebook,
                          float* __restrict__ ws)
{
    __shared__ __align__(16) float buf[2][FB * BLKF];   // 2 x 8 KB
    __shared__ float part[4][2][8];

    const int tid   = threadIdx.x;
    const int lane  = tid & 63;
    const int wid   = tid >> 6;
    const int gslot = wid >> 1;            // which half of the 256-float row
    const int term  = blockIdx.z;
    const int b     = blockIdx.y;
    const float* eptr = (term == 0) ? embed1 : embed2;
    const float* rptr = (term == 0) ? rids2  : rids1;

    const int c0 = __builtin_amdgcn_readfirstlane((wid & 1) * 8);   // SGPR c-base

    const int lbase = blockIdx.x * BLKF;
    const float* eslice = eptr + (size_t)b * F * L + lbase;
    const int myidx = gslot * 64 + lane;   // float2 index within a row [0,128)

    float dotx[8], doty[8];
    #pragma unroll
    for (int j = 0; j < 8; ++j) { dotx[j] = 0.f; doty[j] = 0.f; }
    float e2x = 0.f, e2y = 0.f;

    // prologue: stage tile 0 (each wave DMAs its two f-rows)
    {
        const float* g = eslice + (size_t)(wid * 2) * L + lane * 4;
        dma16(&buf[0][(wid * 2 + 0) * BLKF], g);
        dma16(&buf[0][(wid * 2 + 1) * BLKF], g + L);
    }

    #pragma unroll
    for (int t = 0; t < NT; ++t) {
        if (t + 1 < NT) {
            // issue DMA for tile t+1 into the other buffer, then wait only for
            // tile t's own 2 loads (leave the new 2 in flight)
            const float* g = eslice + (size_t)((t + 1) * FB + wid * 2) * L + lane * 4;
            float* d = &buf[(t + 1) & 1][(wid * 2) * BLKF];
            dma16(d, g);
            dma16(d + BLKF, g + L);
            asm volatile("s_waitcnt vmcnt(2)" ::: "memory");
        } else {
            asm volatile("s_waitcnt vmcnt(0)" ::: "memory");
        }
        __builtin_amdgcn_sched_barrier(0);
        __builtin_amdgcn_s_barrier();          // all waves' tile-t rows visible
        __builtin_amdgcn_sched_barrier(0);

        const float2* lb = (const float2*)buf[t & 1];
        #pragma unroll
        for (int u = 0; u < FB; ++u) {
            const float2 ev = lb[u * 128 + myidx];
            e2x = fmaf(ev.x, ev.x, e2x);
            e2y = fmaf(ev.y, ev.y, e2y);
            #pragma unroll
            for (int j = 0; j < 8; ++j) {
                const float w = codebook[(t * FB + u) * C + c0 + j];  // SGPR bcast
                dotx[j] = fmaf(ev.x, w, dotx[j]);
                doty[j] = fmaf(ev.y, w, doty[j]);
            }
        }
        // all lgkm (ds_read) results consumed by the fmas above; barrier so no
        // wave's next-iter DMA can overwrite a buffer someone still reads
        __builtin_amdgcn_s_barrier();
    }

    // epilogue: 8 r float2 loads in flight, fold, wave-reduce, block-combine
    const float* rslice = rptr + (size_t)b * C * L + lbase;
    {
        float2 rv[8];
        #pragma unroll
        for (int j = 0; j < 8; ++j)
            rv[j] = *(const float2*)(rslice + (size_t)(c0 + j) * L + myidx * 2);
        __builtin_amdgcn_sched_barrier(0);
        #pragma unroll
        for (int j = 0; j < 8; ++j) {
            float num = fmaf(-2.f, dotx[j], e2x) * rv[j].x
                      + fmaf(-2.f, doty[j], e2y) * rv[j].y;
            float den = rv[j].x + rv[j].y;
            #pragma unroll
            for (int off = 32; off > 0; off >>= 1) {
                num += __shfl_down(num, off, 64);
                den += __shfl_down(den, off, 64);
            }
            if (lane == 0) { part[wid][0][j] = num; part[wid][1][j] = den; }
        }
    }
    __syncthreads();

    if (tid < 2 * C) {
        const int p = tid >> 4, c = tid & 15;
        const int chalf = c >> 3, j = c & 7;
        const float v = part[chalf][p][j] + part[chalf + 2][p][j];
        const int rep = blockIdx.x & (NREP - 1);
        atomicAdd(ws + ((((size_t)rep * 2 + term) * 2 + p) * B + b) * C + c, v);
    }
}

// Stage 2: single block. cross = (num + cb2[c]*den)/(den+EPS); plus dist/reg losses.
__global__ __launch_bounds__(256)
void finalize_kernel(const float* __restrict__ codebook,
                     const float* __restrict__ ws,
                     float* __restrict__ out)
{
    __shared__ float cbs[F * C];
    __shared__ float cb2[C];
    __shared__ float red[256];
    __shared__ float redv[256];
    const int tid = threadIdx.x;
    ((float4*)cbs)[tid] = ((const float4*)codebook)[tid];
    __syncthreads();
    if (tid < C) {
        float s = 0.f;
        for (int f = 0; f < F; ++f) { const float v = cbs[f * C + tid]; s = fmaf(v, v, s); }
        cb2[tid] = s;
    }
    __syncthreads();

    // l_cross: 256 entries = [term(2)][b(8)][c(16)]
    {
        const int term = tid >> 7, rem = tid & 127;
        const int b = rem >> 4, c = rem & 15;
        float num = 0.f, den = 0.f;
        for (int rep = 0; rep < NREP; ++rep) {
            num += ws[((((size_t)rep * 2 + term) * 2 + 0) * B + b) * C + c];
            den += ws[((((size_t)rep * 2 + term) * 2 + 1) * B + b) * C + c];
        }
        const bool valid = (den != 0.f);
        red[tid]  = valid ? (num + cb2[c] * den) / (den + EPS) : 0.f;
        redv[tid] = valid ? 1.f : 0.f;
    }
    __syncthreads();
    if (tid == 0) {
        float s0 = 0.f, n0 = 0.f, s1 = 0.f, n1 = 0.f;
        for (int i = 0;   i < 128; ++i) { s0 += red[i]; n0 += redv[i]; }
        for (int i = 128; i < 256; ++i) { s1 += red[i]; n1 += redv[i]; }
        out[0] = s0 / n0 + s1 / n1;
    }
    __syncthreads();

    // l_dist: 256 (ci,cj) pairs, diagonal included exactly as reference
    {
        const int ci = tid & 15, cj = tid >> 4;
        float sq = 0.f;
        for (int f = 0; f < F; ++f) {
            const float d = cbs[f * C + ci] - cbs[f * C + cj];
            sq = fmaf(d, d, sq);
        }
        const float dist = (sq > 0.f) ? sqrtf(sq) : 0.f;
        const float h = fmaxf(2.f * 1.0f - dist, 0.f);
        red[tid] = h * h;
    }
    __syncthreads();
    if (tid == 0) {
        float s = 0.f;
        for (int i = 0; i < 256; ++i) s += red[i];
        out[1] = s / (2.f * C * (C - 1));
        float rg = 0.f;
        for (int c = 0; c < C; ++c) rg += sqrtf(cb2[c]);
        out[2] = rg / C;
    }
}

extern "C" void kernel_launch(void* const* d_in, const int* in_sizes, int n_in,
                              void* d_out, int out_size, void* d_ws, size_t ws_size,
                              hipStream_t stream)
{
    const float* e1 = (const float*)d_in[0];
    const float* r1 = (const float*)d_in[1];
    const float* e2 = (const float*)d_in[2];
    const float* r2 = (const float*)d_in[3];
    const float* cb = (const float*)d_in[4];
    float* out = (float*)d_out;
    float* ws  = (float*)d_ws;

    // zero the NREP*2*2*B*C accumulator block (16 KB)
    hipMemsetAsync(ws, 0, (size_t)NREP * 2 * 2 * B * C * sizeof(float), stream);

    dim3 grid(L / BLKF, B, 2);   // 256 x 8 x 2 = 4096 blocks
    cross_partial_kernel<<<grid, TPB, 0, stream>>>(e1, r1, e2, r2, cb, ws);
    finalize_kernel<<<1, 256, 0, stream>>>(cb, ws, out);
}

// Round 8
// 77.277 us; speedup vs baseline: 6.4178x; 6.4178x over previous
//
#include <hip/hip_runtime.h>
#include <math.h>

#define EPS 1e-6f

constexpr int B    = 8;
constexpr int F    = 64;
constexpr int C    = 16;
constexpr int L    = 65536;      // 256*256
constexpr int TPB  = 256;
constexpr int NREP = 8;          // atomic-target replicas
constexpr int BLKF = 256;        // l-floats per block
constexpr int FB   = 8;          // f-rows per LDS tile (8 KB)
constexpr int NT   = F / FB;     // 8 tiles

// Stage 1: partials num[b,c] = sum_l (e2 - 2*dot)*r, den[b,c] = sum_l r.
// ws layout: float ws[NREP][2][2][B][C] -> [rep][term][num/den][b][c]
//
// R7 lesson: global_load_lds DMA amplified HBM traffic 8.7x (1.43 GB fetch +
// 409 MB phantom writes) though the pipeline sustained 3.55 TB/s at 90% occ.
// Keep the double-buffered tile pipeline, swap the DMA for T14 reg-staging:
// issue 2 coalesced float4 loads (normal cached path -> L3 reuse restored),
// compute current tile from LDS, then ds_write the staged tile. The ds_write
// dependency pins the staged values in VGPRs (no R5/R6-style collapse);
// sched_barrier(0) pins the load-issue point. 8 blocks/CU x 8 KB = 64 KB/CU
// in flight >> ~12 KB BW*latency product.
__global__ __launch_bounds__(TPB, 8)
void cross_partial_kernel(const float* __restrict__ embed1,
                          const float* __restrict__ rids1,
                          const float* __restrict__ embed2,
                          const float* __restrict__ rids2,
                          const float* __restrict__ codebook,
                          float* __restrict__ ws)
{
    __shared__ __align__(16) float buf[2][FB * BLKF];   // 2 x 8 KB
    __shared__ float part[4][2][8];

    const int tid   = threadIdx.x;
    const int lane  = tid & 63;
    const int wid   = tid >> 6;
    const int gslot = wid >> 1;            // which half of the 256-float row
    const int term  = blockIdx.z;
    const int b     = blockIdx.y;
    const float* eptr = (term == 0) ? embed1 : embed2;
    const float* rptr = (term == 0) ? rids2  : rids1;

    const int c0 = __builtin_amdgcn_readfirstlane((wid & 1) * 8);   // SGPR c-base

    const int lbase = blockIdx.x * BLKF;
    const float* eslice = eptr + (size_t)b * F * L + lbase;
    const int myidx = gslot * 64 + lane;   // float2 index within a row [0,128)

    float dotx[8], doty[8];
    #pragma unroll
    for (int j = 0; j < 8; ++j) { dotx[j] = 0.f; doty[j] = 0.f; }
    float e2x = 0.f, e2y = 0.f;

    // prologue: reg-stage tile 0 (each wave: 2 f-rows, 1 KB each), write to LDS
    {
        const float* g = eslice + (size_t)(wid * 2) * L + lane * 4;
        const float4 pa = *(const float4*)g;
        const float4 pb = *(const float4*)(g + L);
        ((float4*)&buf[0][(wid * 2 + 0) * BLKF])[lane] = pa;
        ((float4*)&buf[0][(wid * 2 + 1) * BLKF])[lane] = pb;
    }
    __syncthreads();

    #pragma unroll 1
    for (int t = 0; t < NT; ++t) {
        // phase A: issue next tile's loads (coalesced float4, cached path)
        float4 na, nb;
        const bool more = (t + 1 < NT);
        if (more) {
            const float* g = eslice + (size_t)((t + 1) * FB + wid * 2) * L + lane * 4;
            na = *(const float4*)g;
            nb = *(const float4*)(g + L);
        }
        __builtin_amdgcn_sched_barrier(0);   // pin: loads issue before compute

        // phase B: compute tile t from LDS (HBM latency hides under this)
        const float2* lb = (const float2*)buf[t & 1];
        #pragma unroll
        for (int u = 0; u < FB; ++u) {
            const float2 ev = lb[u * 128 + myidx];
            e2x = fmaf(ev.x, ev.x, e2x);
            e2y = fmaf(ev.y, ev.y, e2y);
            #pragma unroll
            for (int j = 0; j < 8; ++j) {
                const float w = codebook[(t * FB + u) * C + c0 + j];  // SGPR bcast
                dotx[j] = fmaf(ev.x, w, dotx[j]);
                doty[j] = fmaf(ev.y, w, doty[j]);
            }
        }

        // phase C: write staged tile into the other buffer; one barrier per tile
        // (prev iter's barrier already guarantees everyone finished reading it)
        if (more) {
            float* d = &buf[(t + 1) & 1][(wid * 2) * BLKF];
            ((float4*)d)[lane] = na;
            ((float4*)(d + BLKF))[lane] = nb;
        }
        __syncthreads();
    }

    // epilogue: 8 r float2 loads in flight, fold, wave-reduce, block-combine
    const float* rslice = rptr + (size_t)b * C * L + lbase;
    {
        float2 rv[8];
        #pragma unroll
        for (int j = 0; j < 8; ++j)
            rv[j] = *(const float2*)(rslice + (size_t)(c0 + j) * L + myidx * 2);
        __builtin_amdgcn_sched_barrier(0);
        #pragma unroll
        for (int j = 0; j < 8; ++j) {
            float num = fmaf(-2.f, dotx[j], e2x) * rv[j].x
                      + fmaf(-2.f, doty[j], e2y) * rv[j].y;
            float den = rv[j].x + rv[j].y;
            #pragma unroll
            for (int off = 32; off > 0; off >>= 1) {
                num += __shfl_down(num, off, 64);
                den += __shfl_down(den, off, 64);
            }
            if (lane == 0) { part[wid][0][j] = num; part[wid][1][j] = den; }
        }
    }
    __syncthreads();

    if (tid < 2 * C) {
        const int p = tid >> 4, c = tid & 15;
        const int chalf = c >> 3, j = c & 7;
        const float v = part[chalf][p][j] + part[chalf + 2][p][j];
        const int rep = blockIdx.x & (NREP - 1);
        atomicAdd(ws + ((((size_t)rep * 2 + term) * 2 + p) * B + b) * C + c, v);
    }
}

// Stage 2: single block. cross = (num + cb2[c]*den)/(den+EPS); plus dist/reg losses.
__global__ __launch_bounds__(256)
void finalize_kernel(const float* __restrict__ codebook,
                     const float* __restrict__ ws,
                     float* __restrict__ out)
{
    __shared__ float cbs[F * C];
    __shared__ float cb2[C];
    __shared__ float red[256];
    __shared__ float redv[256];
    const int tid = threadIdx.x;
    ((float4*)cbs)[tid] = ((const float4*)codebook)[tid];
    __syncthreads();
    if (tid < C) {
        float s = 0.f;
        for (int f = 0; f < F; ++f) { const float v = cbs[f * C + tid]; s = fmaf(v, v, s); }
        cb2[tid] = s;
    }
    __syncthreads();

    // l_cross: 256 entries = [term(2)][b(8)][c(16)]
    {
        const int term = tid >> 7, rem = tid & 127;
        const int b = rem >> 4, c = rem & 15;
        float num = 0.f, den = 0.f;
        for (int rep = 0; rep < NREP; ++rep) {
            num += ws[((((size_t)rep * 2 + term) * 2 + 0) * B + b) * C + c];
            den += ws[((((size_t)rep * 2 + term) * 2 + 1) * B + b) * C + c];
        }
        const bool valid = (den != 0.f);
        red[tid]  = valid ? (num + cb2[c] * den) / (den + EPS) : 0.f;
        redv[tid] = valid ? 1.f : 0.f;
    }
    __syncthreads();
    if (tid == 0) {
        float s0 = 0.f, n0 = 0.f, s1 = 0.f, n1 = 0.f;
        for (int i = 0;   i < 128; ++i) { s0 += red[i]; n0 += redv[i]; }
        for (int i = 128; i < 256; ++i) { s1 += red[i]; n1 += redv[i]; }
        out[0] = s0 / n0 + s1 / n1;
    }
    __syncthreads();

    // l_dist: 256 (ci,cj) pairs, diagonal included exactly as reference
    {
        const int ci = tid & 15, cj = tid >> 4;
        float sq = 0.f;
        for (int f = 0; f < F; ++f) {
            const float d = cbs[f * C + ci] - cbs[f * C + cj];
            sq = fmaf(d, d, sq);
        }
        const float dist = (sq > 0.f) ? sqrtf(sq) : 0.f;
        const float h = fmaxf(2.f * 1.0f - dist, 0.f);
        red[tid] = h * h;
    }
    __syncthreads();
    if (tid == 0) {
        float s = 0.f;
        for (int i = 0; i < 256; ++i) s += red[i];
        out[1] = s / (2.f * C * (C - 1));
        float rg = 0.f;
        for (int c = 0; c < C; ++c) rg += sqrtf(cb2[c]);
        out[2] = rg / C;
    }
}

extern "C" void kernel_launch(void* const* d_in, const int* in_sizes, int n_in,
                              void* d_out, int out_size, void* d_ws, size_t ws_size,
                              hipStream_t stream)
{
    const float* e1 = (const float*)d_in[0];
    const float* r1 = (const float*)d_in[1];
    const float* e2 = (const float*)d_in[2];
    const float* r2 = (const float*)d_in[3];
    const float* cb = (const float*)d_in[4];
    float* out = (float*)d_out;
    float* ws  = (float*)d_ws;

    // zero the NREP*2*2*B*C accumulator block (16 KB)
    hipMemsetAsync(ws, 0, (size_t)NREP * 2 * 2 * B * C * sizeof(float), stream);

    dim3 grid(L / BLKF, B, 2);   // 256 x 8 x 2 = 4096 blocks
    cross_partial_kernel<<<grid, TPB, 0, stream>>>(e1, r1, e2, r2, cb, ws);
    finalize_kernel<<<1, 256, 0, stream>>>(cb, ws, out);
}